// Round 6
// baseline (859.593 us; speedup 1.0000x reference)
//
#include <hip/hip_runtime.h>
#include <hip/hip_bf16.h>

typedef __hip_bfloat16 bf16;
typedef __attribute__((ext_vector_type(8))) short bf16x8;
typedef __attribute__((ext_vector_type(4))) float f32x4;

#define CPIX 12288          // pixels per chunk (64 rows * 192 cols)

__device__ __forceinline__ float tof(bf16 x){ return __bfloat162float(x); }
__device__ __forceinline__ bf16  tob(float x){ return __float2bfloat16(x); }
__device__ __forceinline__ float bf2f(short s){ return __uint_as_float(((unsigned)(unsigned short)s) << 16); }

// ---------------- weight permute+convert (f32 -> bf16), once per launch; also zeroes rms accum ----------------
// Packed channel order: n = role*384 + h*48 + e.  Source col:
//   values path: e<32 -> W_vqk col 24e+3h+role (normalized part); e>=32 -> W_vv col 24e+3h+role-768
//   coords path: role in {0,1} -> W_cqk col 16e+2h+role
__global__ __launch_bounds__(256) void wprep_k(
    const float* __restrict__ W_vqk, const float* __restrict__ W_vv, const float* __restrict__ W_cqk,
    const float* __restrict__ W_ov,  const float* __restrict__ b_vqk, const float* __restrict__ b_vv,
    const float* __restrict__ b_cqk, const float* __restrict__ g_vqk, const float* __restrict__ g_cqk,
    bf16* __restrict__ W1Tp, bf16* __restrict__ WcTp, bf16* __restrict__ WoT,
    float* __restrict__ bP0, float* __restrict__ bPc, float* __restrict__ gvP, float* __restrict__ gcP,
    float* __restrict__ rs_v, float* __restrict__ rs_c)
{
  int idx = blockIdx.x*256 + threadIdx.x;
  if (idx < 442368) {                     // W1Tp [1152][384]
    int n = idx/384, k = idx - n*384;
    int role = n/384, rem = n - role*384, h = rem/48, e = rem - (rem/48)*48;
    int c = 24*e + 3*h + role;
    float v = (e < 32) ? W_vqk[k*768 + c] : W_vv[k*384 + (c - 768)];
    W1Tp[n*384 + k] = tob(v);
  } else if (idx < 540672) {              // WcTp [768][128]
    int q = idx - 442368;
    int n = q >> 7, k = q & 127;
    int role = n/384, rem = n - role*384, h = rem/48, e = rem - (rem/48)*48;
    WcTp[n*128 + k] = tob(W_cqk[k*768 + 16*e + 2*h + role]);
  } else if (idx < 688128) {              // WoT [384][384]
    int q = idx - 540672;
    int n = q/384, k = q - n*384;
    WoT[n*384 + k] = tob(W_ov[k*384 + n]);
  } else if (idx < 689280) {              // bP0 [1152]
    int n = idx - 688128;
    int role = n/384, rem = n - role*384, h = rem/48, e = rem - (rem/48)*48;
    int c = 24*e + 3*h + role;
    bP0[n] = (e < 32) ? b_vqk[c] : b_vv[c - 768];
  } else if (idx < 690048) {              // bPc [768]
    int n = idx - 689280;
    int role = n/384, rem = n - role*384, h = rem/48, e = rem - (rem/48)*48;
    bPc[n] = b_cqk[16*e + 2*h + role];
  } else if (idx < 691200) {              // gvP [1152]: 1.0 for raw (e>=32) channels
    int n = idx - 690048;
    int role = n/384, rem = n - role*384, h = rem/48, e = rem - (rem/48)*48;
    gvP[n] = (e < 32) ? g_vqk[24*e + 3*h + role] : 1.0f;
  } else if (idx < 691968) {              // gcP [768]
    int n = idx - 691200;
    int role = n/384, rem = n - role*384, h = rem/48, e = rem - (rem/48)*48;
    gcP[n] = g_cqk[16*e + 2*h + role];
  } else if (idx < 716544) {              // zero rms accumulators for chunk 0
    int q = idx - 691968;
    if (q < CPIX) rs_v[q] = 0.f; else rs_c[q - CPIX] = 0.f;
  }
}

// ---------------- fused Q/K projection GEMM (values + coords in ONE dispatch) ----------------
// grid (96, 15): blockIdx.y in [0,9) -> values path (KTOT=384, NT=1152, Y0, rs_v += qk v^2)
//                blockIdx.y in [9,15) -> coords path (KTOT=128, NT=768, Yc, rs_c += v^2)
// 128x128 tile, BK=64, 2-stage register prefetch: next K-step's A(f32)+B(bf16) loads issued
// right after the barrier so HBM latency hides under the 32-MFMA compute phase.
// A is the rolled gather of the f32 input (fused roll + f32->bf16 during LDS write).
__global__ __launch_bounds__(256,3) void gemmqk_k(
    const float* __restrict__ Vf, const float* __restrict__ Cf,
    const bf16* __restrict__ W1Tp, const bf16* __restrict__ WcTp,
    const float* __restrict__ bP0, const float* __restrict__ bPc,
    bf16* __restrict__ Y0, bf16* __restrict__ Yc,
    float* __restrict__ rs_v, float* __restrict__ rs_c,
    int bb, int hf)
{
  const bool isc = (blockIdx.y >= 9);
  const int KTOT = isc ? 128 : 384;
  const int NT   = isc ? 768 : 1152;
  const float* Af = isc ? Cf : Vf;
  const bf16*  WT = isc ? WcTp : W1Tp;
  const float* biasP = isc ? bPc : bP0;
  bf16* outb  = isc ? Yc : Y0;
  float* rsum = isc ? rs_c : rs_v;
  const int nbase   = (isc ? (blockIdx.y - 9) : blockIdx.y)*128;
  const int rowbase = blockIdx.x*128;

  __shared__ bf16 As[128][72];      // +8 pad: 2-way-max bank aliasing on b128 reads
  __shared__ bf16 Bs[128][72];
  const int tid = threadIdx.x, lane = tid & 63, wid = tid >> 6;
  const int wr = (wid >> 1)*64, wc = (wid & 1)*64;

  // per-thread A-chunk base offsets (4 chunks, idx = it*256+tid -> (r,c)); rolled source pixel
  unsigned abase[4];
  #pragma unroll
  for (int it = 0; it < 4; it++) {
    int idx = it*256 + tid, r = idx >> 3, c = idx & 7;
    int pix = rowbase + r;
    int lr = pix/192, lc = pix - (pix/192)*192;
    int srow = (hf*64 + lr + 4) % 192;    // jnp.roll(t,-4)
    int scol = (lc + 4) % 192;
    abase[it] = (unsigned)(((bb*192 + srow)*192 + scol)*KTOT + c*8);
  }

  float4 pa[4][2];                  // staged A (f32), 32 VGPR
  uint4  pb[4];                     // staged B (bf16), 16 VGPR

  #pragma unroll
  for (int it = 0; it < 4; it++) {  // prologue loads, ks=0
    const float* s = Af + abase[it];
    pa[it][0] = *(const float4*)s;  pa[it][1] = *(const float4*)(s + 4);
    int idx = it*256 + tid, r = idx >> 3, c = idx & 7;
    pb[it] = *(const uint4*)(WT + (size_t)(nbase + r)*KTOT + c*8);
  }

  f32x4 acc[4][4] = {};
  for (int ks = 0; ks < KTOT; ks += 64) {
    #pragma unroll
    for (int it = 0; it < 4; it++) {    // write staged regs -> LDS (f32->bf16 for A)
      int idx = it*256 + tid, r = idx >> 3, c = idx & 7;
      union { bf16 h[8]; uint4 u4; } t;
      t.h[0]=tob(pa[it][0].x); t.h[1]=tob(pa[it][0].y); t.h[2]=tob(pa[it][0].z); t.h[3]=tob(pa[it][0].w);
      t.h[4]=tob(pa[it][1].x); t.h[5]=tob(pa[it][1].y); t.h[6]=tob(pa[it][1].z); t.h[7]=tob(pa[it][1].w);
      *(uint4*)&As[r][c*8] = t.u4;
      *(uint4*)&Bs[r][c*8] = pb[it];
    }
    __syncthreads();
    if (ks + 64 < KTOT) {               // prefetch next K-step; overlaps the MFMAs below
      #pragma unroll
      for (int it = 0; it < 4; it++) {
        const float* s = Af + abase[it] + (ks + 64);
        pa[it][0] = *(const float4*)s;  pa[it][1] = *(const float4*)(s + 4);
        int idx = it*256 + tid, r = idx >> 3, c = idx & 7;
        pb[it] = *(const uint4*)(WT + (size_t)(nbase + r)*KTOT + (ks + 64) + c*8);
      }
    }
    #pragma unroll
    for (int k2 = 0; k2 < 64; k2 += 32) {
      const int kb = k2 + (lane >> 4)*8, ml = lane & 15;
      bf16x8 a[4], b[4];
      #pragma unroll
      for (int t = 0; t < 4; t++) { a[t] = *(const bf16x8*)&As[wr + t*16 + ml][kb];
                                    b[t] = *(const bf16x8*)&Bs[wc + t*16 + ml][kb]; }
      #pragma unroll
      for (int mt = 0; mt < 4; mt++)
      #pragma unroll
      for (int nt = 0; nt < 4; nt++)
        acc[mt][nt] = __builtin_amdgcn_mfma_f32_16x16x32_bf16(a[mt], b[nt], acc[mt][nt], 0, 0, 0);
    }
    __syncthreads();
  }
  // epilogue: C/D layout col=lane&15, row=(lane>>4)*4+reg; fused bias + rms partial sums
  const int lr4 = (lane >> 4)*4, lcol = lane & 15;
  #pragma unroll
  for (int mt = 0; mt < 4; mt++) {
    #pragma unroll
    for (int i = 0; i < 4; i++) {
      int pix = rowbase + wr + mt*16 + lr4 + i;
      float sq_ = 0.f;
      #pragma unroll
      for (int nt = 0; nt < 4; nt++) {
        int n = nbase + wc + nt*16 + lcol;
        float v = acc[mt][nt][i] + biasP[n];
        outb[(size_t)pix*NT + n] = tob(v);
        if (isc || (n % 48) < 32) sq_ += v*v;   // qk-normalized channels only (values path)
      }
      sq_ += __shfl_xor(sq_, 1); sq_ += __shfl_xor(sq_, 2);
      sq_ += __shfl_xor(sq_, 4); sq_ += __shfl_xor(sq_, 8);
      if (lcol == 0) atomicAdd(&rsum[pix], sq_);
    }
  }
}

// ---------------- output projection GEMM: y_att bf16 [CPIX][384] @ WoT -> out f32 (+bias) ----------------
// grid (192,3), 64-row tiles, register-prefetch K-loop; also zeroes rms accum for the next chunk.
__global__ __launch_bounds__(256,4) void gemmo_k(const bf16* __restrict__ Ab, const bf16* __restrict__ WT,
    const float* __restrict__ biasP, float* __restrict__ outf,
    float* __restrict__ z0, float* __restrict__ z1, int pix0)
{
  __shared__ bf16 As[64][72];
  __shared__ bf16 Bs[128][72];
  const int tid = threadIdx.x, lane = tid & 63, wid = tid >> 6;
  const int wr = (wid >> 1)*32, wc = (wid & 1)*64;
  const int rowbase = blockIdx.x*64;
  const int nbase   = blockIdx.y*128;

  if (blockIdx.y == 0) {            // zero rms accumulators for the NEXT chunk (stream-ordered)
    if (tid < 64) z0[rowbase + tid] = 0.f;
    else if (tid < 128) z1[rowbase + tid - 64] = 0.f;
  }

  uint4 pa[2], pb[4];
  #pragma unroll
  for (int it = 0; it < 2; it++) {  // A: 512 chunks -> 2/thread
    int idx = it*256 + tid, r = idx >> 3, c = idx & 7;
    pa[it] = *(const uint4*)(Ab + (size_t)(rowbase + r)*384 + c*8);
  }
  #pragma unroll
  for (int it = 0; it < 4; it++) {  // B: 1024 chunks -> 4/thread
    int idx = it*256 + tid, r = idx >> 3, c = idx & 7;
    pb[it] = *(const uint4*)(WT + (size_t)(nbase + r)*384 + c*8);
  }

  f32x4 acc[2][4] = {};
  for (int ks = 0; ks < 384; ks += 64) {
    #pragma unroll
    for (int it = 0; it < 2; it++) {
      int idx = it*256 + tid, r = idx >> 3, c = idx & 7;
      *(uint4*)&As[r][c*8] = pa[it];
    }
    #pragma unroll
    for (int it = 0; it < 4; it++) {
      int idx = it*256 + tid, r = idx >> 3, c = idx & 7;
      *(uint4*)&Bs[r][c*8] = pb[it];
    }
    __syncthreads();
    if (ks + 64 < 384) {
      #pragma unroll
      for (int it = 0; it < 2; it++) {
        int idx = it*256 + tid, r = idx >> 3, c = idx & 7;
        pa[it] = *(const uint4*)(Ab + (size_t)(rowbase + r)*384 + (ks + 64) + c*8);
      }
      #pragma unroll
      for (int it = 0; it < 4; it++) {
        int idx = it*256 + tid, r = idx >> 3, c = idx & 7;
        pb[it] = *(const uint4*)(WT + (size_t)(nbase + r)*384 + (ks + 64) + c*8);
      }
    }
    #pragma unroll
    for (int k2 = 0; k2 < 64; k2 += 32) {
      const int kb = k2 + (lane >> 4)*8, ml = lane & 15;
      bf16x8 a[2], b[4];
      #pragma unroll
      for (int t = 0; t < 2; t++) a[t] = *(const bf16x8*)&As[wr + t*16 + ml][kb];
      #pragma unroll
      for (int t = 0; t < 4; t++) b[t] = *(const bf16x8*)&Bs[wc + t*16 + ml][kb];
      #pragma unroll
      for (int mt = 0; mt < 2; mt++)
      #pragma unroll
      for (int nt = 0; nt < 4; nt++)
        acc[mt][nt] = __builtin_amdgcn_mfma_f32_16x16x32_bf16(a[mt], b[nt], acc[mt][nt], 0, 0, 0);
    }
    __syncthreads();
  }
  const int lr4 = (lane >> 4)*4, lcol = lane & 15;
  #pragma unroll
  for (int mt = 0; mt < 2; mt++)
  #pragma unroll
  for (int nt = 0; nt < 4; nt++) {
    f32x4 av = acc[mt][nt];
    int n = nbase + wc + nt*16 + lcol;
    float bv = biasP[n];
    #pragma unroll
    for (int i = 0; i < 4; i++) {
      int pix = rowbase + wr + mt*16 + lr4 + i;
      outf[(size_t)(pix0 + pix)*384 + n] = av[i] + bv;
    }
  }
}

// ---------------- helpers for MFMA attention ----------------
__device__ __forceinline__ bf16x8 pack8g(uint4 raw, float r, float4 ga, float4 gb)
{
  union { uint4 u4; unsigned short us[8]; } rw; rw.u4 = raw;
  union { bf16x8 v; bf16 h[8]; } o;
  o.h[0] = tob(bf2f((short)rw.us[0]) * (r * ga.x));
  o.h[1] = tob(bf2f((short)rw.us[1]) * (r * ga.y));
  o.h[2] = tob(bf2f((short)rw.us[2]) * (r * ga.z));
  o.h[3] = tob(bf2f((short)rw.us[3]) * (r * ga.w));
  o.h[4] = tob(bf2f((short)rw.us[4]) * (r * gb.x));
  o.h[5] = tob(bf2f((short)rw.us[5]) * (r * gb.y));
  o.h[6] = tob(bf2f((short)rw.us[6]) * (r * gb.z));
  o.h[7] = tob(bf2f((short)rw.us[7]) * (r * gb.w));
  return o.v;
}

__device__ __forceinline__ float rmsf(float s){ return rsqrtf(s*(1.f/768.f) + 1e-6f); }

// ---------------- windowed attention via MFMA: block per (window, head) ----------------
// 4 waves row-split (16 S-rows each). QK^T: A-frag (Q) loaded direct from global into regs
// (scaled q' in bf16), B-frag (K') from LDS.  Softmax fully in-register (row lives in a
// 16-lane group).  P (bf16, un-normalized exp) through LDS only for the PV A-fragment;
// V staged transposed; 1/rowsum applied to PV output.  rms = rsqrt computed inline from raw sums.
__global__ __launch_bounds__(256,5) void attn_k(const bf16* __restrict__ Y0, const bf16* __restrict__ Yc,
    const float* __restrict__ rs_v, const float* __restrict__ rs_c,
    const float* __restrict__ gvP, const float* __restrict__ gcP,
    const float* __restrict__ lam_p, const float* __restrict__ pos,
    bf16* __restrict__ y_att, int hf)
{
  __shared__ bf16 Ks[64][104];     // k' rows [j][96], +8 pad (208B stride, 16B-mult)
  __shared__ bf16 Vt[48][72];      // v' transposed [e][64], +8 pad
  __shared__ bf16 Pb[64][72];      // P bf16 (per-wave-private rows); reused for O repack
  __shared__ float sq[96];         // q channel scale: g*SCL (values) / g*lam*SCL (coords)
  __shared__ float poss[225];      // rel-pos bias table 15x15
  const int tid = threadIdx.x, lane = tid & 63, w = tid >> 6;
  const int win = blockIdx.x, h = blockIdx.y;
  const int wx = win/24, wy = win - (win/24)*24;
  const float lam = lam_p[0];
  const float SCL = 0.14433756729740643f;   // 1/sqrt(48)

  if (tid < 96) sq[tid] = (tid < 48 ? gvP[h*48 + tid] : gcP[h*48 + tid - 48]*lam) * SCL;
  if (tid < 225) poss[tid] = pos[tid];

  // ---- stage K' (values+coords) and V' (transposed), 18 wave-uniform groups ----
  {
    const int j = lane;
    const int p = (wx*8 + (j>>3))*192 + wy*8 + (j&7);
    const float rvj = rmsf(rs_v[p]), rcj = rmsf(rs_c[p]);
    for (int grp = w; grp < 18; grp += 4) {
      if (grp < 6) {                        // K values part: e = c*8..c*8+7
        int c = grp;
        uint4 raw = *(const uint4*)(Y0 + (size_t)p*1152 + 384 + h*48 + c*8);
        const float* gp = gvP + 384 + h*48 + c*8;
        float4 ga = *(const float4*)gp, gb = *(const float4*)(gp+4);
        float r = (c < 4) ? rvj : 1.0f;     // e<32 normalized, e>=32 raw
        union { bf16x8 v; uint4 u4; } o; o.v = pack8g(raw, r, ga, gb);
        *(uint4*)&Ks[j][c*8] = o.u4;
      } else if (grp < 12) {                // K coords part -> k' cols 48..95
        int c = grp - 6;
        uint4 raw = *(const uint4*)(Yc + (size_t)p*768 + 384 + h*48 + c*8);
        const float* gp = gcP + 384 + h*48 + c*8;
        float4 ga = *(const float4*)gp, gb = *(const float4*)(gp+4);
        union { bf16x8 v; uint4 u4; } o; o.v = pack8g(raw, rcj, ga, gb);
        *(uint4*)&Ks[j][48 + c*8] = o.u4;
      } else {                              // V -> transposed Vt[e][j]
        int c = grp - 12;
        uint4 raw = *(const uint4*)(Y0 + (size_t)p*1152 + 768 + h*48 + c*8);
        const float* gp = gvP + 768 + h*48 + c*8;
        float4 ga = *(const float4*)gp, gb = *(const float4*)(gp+4);
        float r = (c < 4) ? rvj : 1.0f;
        union { uint4 u4; unsigned short us[8]; } rw; rw.u4 = raw;
        Vt[c*8+0][j] = tob(bf2f((short)rw.us[0]) * (r * ga.x));
        Vt[c*8+1][j] = tob(bf2f((short)rw.us[1]) * (r * ga.y));
        Vt[c*8+2][j] = tob(bf2f((short)rw.us[2]) * (r * ga.z));
        Vt[c*8+3][j] = tob(bf2f((short)rw.us[3]) * (r * ga.w));
        Vt[c*8+4][j] = tob(bf2f((short)rw.us[4]) * (r * gb.x));
        Vt[c*8+5][j] = tob(bf2f((short)rw.us[5]) * (r * gb.y));
        Vt[c*8+6][j] = tob(bf2f((short)rw.us[6]) * (r * gb.z));
        Vt[c*8+7][j] = tob(bf2f((short)rw.us[7]) * (r * gb.w));
      }
    }
  }
  __syncthreads();                          // the only block-wide barrier

  // ---- Q fragments direct from global (A-frag: row = lane&15, k = (lane>>4)*8 + kb) ----
  const int ml = lane & 15, k0 = (lane >> 4)*8;
  const int mrow = w*16 + ml;
  const int pA = (wx*8 + (mrow>>3))*192 + wy*8 + (mrow&7);
  const float rvA = rmsf(rs_v[pA]), rcA = rmsf(rs_c[pA]);
  bf16x8 qf0, qf1, qf2;
  {
    uint4 r0 = *(const uint4*)(Y0 + (size_t)pA*1152 + h*48 + k0);            // k in [0,32): values, rms
    float4 ga = *(const float4*)&sq[k0],      gb = *(const float4*)&sq[k0+4];
    qf0 = pack8g(r0, rvA, ga, gb);
    const bf16* s1 = (k0 < 16) ? (Y0 + (size_t)pA*1152 + h*48 + 32 + k0)     // k in [32,48): values raw
                               : (Yc + (size_t)pA*768  + h*48 + (k0 - 16));  // k in [48,64): coords
    float r1 = (k0 < 16) ? 1.0f : rcA;
    uint4 raw1 = *(const uint4*)s1;
    ga = *(const float4*)&sq[32+k0]; gb = *(const float4*)&sq[36+k0];
    qf1 = pack8g(raw1, r1, ga, gb);
    uint4 r2 = *(const uint4*)(Yc + (size_t)pA*768 + h*48 + 16 + k0);        // k in [64,96): coords
    ga = *(const float4*)&sq[64+k0]; gb = *(const float4*)&sq[68+k0];
    qf2 = pack8g(r2, rcA, ga, gb);
  }

  // ---- QK^T: wave w covers S rows [w*16, w*16+16), all 64 cols, K=96 ----
  f32x4 acc[4] = {};
  #pragma unroll
  for (int nt = 0; nt < 4; nt++) {
    bf16x8 b0 = *(const bf16x8*)&Ks[nt*16 + ml][k0];
    bf16x8 b1 = *(const bf16x8*)&Ks[nt*16 + ml][32 + k0];
    bf16x8 b2 = *(const bf16x8*)&Ks[nt*16 + ml][64 + k0];
    acc[nt] = __builtin_amdgcn_mfma_f32_16x16x32_bf16(qf0, b0, acc[nt], 0, 0, 0);
    acc[nt] = __builtin_amdgcn_mfma_f32_16x16x32_bf16(qf1, b1, acc[nt], 0, 0, 0);
    acc[nt] = __builtin_amdgcn_mfma_f32_16x16x32_bf16(qf2, b2, acc[nt], 0, 0, 0);
  }

  // ---- bias + mask + in-register softmax (row = 16-lane group, 4 regs x 4 col-tiles) ----
  const bool rowm = (hf == 2) && (wx == 7);
  const bool colm = (wy == 23);
  const int g4 = (lane >> 4)*4;
  float pv[4][4];
  float inv_[4];
  #pragma unroll
  for (int i = 0; i < 4; i++) {
    int r = w*16 + g4 + i;
    int txi = r >> 3, tyi = r & 7;
    #pragma unroll
    for (int nt = 0; nt < 4; nt++) {
      int j = nt*16 + ml;
      int txj = j >> 3, tyj = j & 7;
      float v = acc[nt][i] + poss[(txj - txi + 7)*15 + (tyj - tyi + 7)];
      if ((rowm && ((txi >= 4) != (txj >= 4))) || (colm && ((tyi >= 4) != (tyj >= 4)))) v = -1e30f;
      pv[i][nt] = v;
    }
    float mx = fmaxf(fmaxf(pv[i][0], pv[i][1]), fmaxf(pv[i][2], pv[i][3]));
    #pragma unroll
    for (int m = 1; m < 16; m <<= 1) mx = fmaxf(mx, __shfl_xor(mx, m));
    float s0 = 0.f;
    #pragma unroll
    for (int nt = 0; nt < 4; nt++) { pv[i][nt] = __expf(pv[i][nt] - mx); s0 += pv[i][nt]; }
    #pragma unroll
    for (int m = 1; m < 16; m <<= 1) s0 += __shfl_xor(s0, m);
    inv_[i] = 1.f / s0;
  }
  #pragma unroll
  for (int i = 0; i < 4; i++)
  #pragma unroll
  for (int nt = 0; nt < 4; nt++)
    Pb[w*16 + g4 + i][nt*16 + ml] = tob(pv[i][nt]);   // un-normalized; 1/sum folded into O

  // ---- PV: O[16x48] per wave, K=64.  A = Pb (own rows), B = Vt (transposed V) ----
  f32x4 o0 = {}, o1 = {}, o2 = {};
  {
    bf16x8 a0 = *(const bf16x8*)&Pb[w*16 + ml][k0];
    bf16x8 b;
    b = *(const bf16x8*)&Vt[ 0 + ml][k0];      o0 = __builtin_amdgcn_mfma_f32_16x16x32_bf16(a0, b, o0, 0, 0, 0);
    b = *(const bf16x8*)&Vt[16 + ml][k0];      o1 = __builtin_amdgcn_mfma_f32_16x16x32_bf16(a0, b, o1, 0, 0, 0);
    b = *(const bf16x8*)&Vt[32 + ml][k0];      o2 = __builtin_amdgcn_mfma_f32_16x16x32_bf16(a0, b, o2, 0, 0, 0);
    bf16x8 a1 = *(const bf16x8*)&Pb[w*16 + ml][32 + k0];
    b = *(const bf16x8*)&Vt[ 0 + ml][32 + k0]; o0 = __builtin_amdgcn_mfma_f32_16x16x32_bf16(a1, b, o0, 0, 0, 0);
    b = *(const bf16x8*)&Vt[16 + ml][32 + k0]; o1 = __builtin_amdgcn_mfma_f32_16x16x32_bf16(a1, b, o1, 0, 0, 0);
    b = *(const bf16x8*)&Vt[32 + ml][32 + k0]; o2 = __builtin_amdgcn_mfma_f32_16x16x32_bf16(a1, b, o2, 0, 0, 0);
  }

  // ---- O repack into Pb (own rows, wave-private) then vectorized global store ----
  #pragma unroll
  for (int i = 0; i < 4; i++) {
    Pb[w*16 + g4 + i][     ml] = tob(o0[i] * inv_[i]);
    Pb[w*16 + g4 + i][16 + ml] = tob(o1[i] * inv_[i]);
    Pb[w*16 + g4 + i][32 + ml] = tob(o2[i] * inv_[i]);
  }
  #pragma unroll
  for (int s2 = 0; s2 < 3; s2++) {
    int u = s2*64 + lane;                 // 192 units: 16 rows x 12 uint2-segments
    int row = u / 12, seg = u - row*12;
    int rr = w*16 + row;
    int pC = (wx*8 + (rr>>3))*192 + wy*8 + (rr&7);
    uint2 d = *(const uint2*)&Pb[rr][seg*4];
    *(uint2*)(y_att + (size_t)pC*384 + h*48 + seg*4) = d;
  }
}

extern "C" void kernel_launch(void* const* d_in, const int* in_sizes, int n_in,
                              void* d_out, int out_size, void* d_ws, size_t ws_size,
                              hipStream_t stream)
{
  const float* values = (const float*)d_in[0];
  const float* coords = (const float*)d_in[1];
  const float* W_vqk  = (const float*)d_in[2];
  const float* b_vqk  = (const float*)d_in[3];
  const float* g_vqk  = (const float*)d_in[4];
  const float* W_vv   = (const float*)d_in[5];
  const float* b_vv   = (const float*)d_in[6];
  const float* W_cqk  = (const float*)d_in[7];
  const float* b_cqk  = (const float*)d_in[8];
  const float* g_cqk  = (const float*)d_in[9];
  const float* lam    = (const float*)d_in[10];
  const float* pos    = (const float*)d_in[11];
  const float* W_ov   = (const float*)d_in[12];
  const float* b_ov   = (const float*)d_in[13];
  float* out = (float*)d_out;

  char* ws = (char*)d_ws;
  bf16*  W1Tp  = (bf16*)(ws + 0);           // 1152*384*2   = 884736
  bf16*  WcTp  = (bf16*)(ws + 884736);      // 768*128*2    = 196608
  bf16*  WoT   = (bf16*)(ws + 1081344);     // 384*384*2    = 294912
  float* bP0   = (float*)(ws + 1376256);    // 1152*4
  float* bPc   = (float*)(ws + 1380864);    // 768*4
  float* gvP   = (float*)(ws + 1383936);    // 1152*4
  float* gcP   = (float*)(ws + 1388544);    // 768*4
  bf16*  Y0    = (bf16*)(ws + 1391616);     // CPIX*1152*2  = 28311552
  bf16*  Yc    = (bf16*)(ws + 29703168);    // CPIX*768*2   = 18874368
  float* rs_v  = (float*)(ws + 48577536);   // CPIX*4  (raw sum-of-squares accumulators)
  float* rs_c  = (float*)(ws + 48626688);   // CPIX*4
  bf16*  y_att = (bf16*)(ws + 48675840);    // CPIX*384*2   = 9437184 -> total 58113024
  (void)ws_size; (void)in_sizes; (void)n_in; (void)out_size;

  wprep_k<<<2799, 256, 0, stream>>>(W_vqk, W_vv, W_cqk, W_ov, b_vqk, b_vv, b_cqk, g_vqk, g_cqk,
                                    W1Tp, WcTp, WoT, bP0, bPc, gvP, gcP, rs_v, rs_c);

  for (int ch = 0; ch < 6; ch++) {
    int bb = ch/3, hf = ch - bb*3;
    gemmqk_k<<<dim3(96,15), 256, 0, stream>>>(values, coords, W1Tp, WcTp, bP0, bPc,
                                              Y0, Yc, rs_v, rs_c, bb, hf);
    attn_k<<<dim3(192,8), 256, 0, stream>>>(Y0, Yc, rs_v, rs_c, gvP, gcP, lam, pos, y_att, hf);
    gemmo_k<<<dim3(192,3), 256, 0, stream>>>(y_att, WoT, b_ov, out, rs_v, rs_c, ch*CPIX);
  }
}

// Round 7
// 691.535 us; speedup vs baseline: 1.2430x; 1.2430x over previous
//
#include <hip/hip_runtime.h>
#include <hip/hip_bf16.h>

typedef __hip_bfloat16 bf16;
typedef __attribute__((ext_vector_type(8))) short bf16x8;
typedef __attribute__((ext_vector_type(4))) float f32x4;

#define CPIX 12288          // pixels per chunk (64 rows * 192 cols)

__device__ __forceinline__ float tof(bf16 x){ return __bfloat162float(x); }
__device__ __forceinline__ bf16  tob(float x){ return __float2bfloat16(x); }
__device__ __forceinline__ float bf2f(short s){ return __uint_as_float(((unsigned)(unsigned short)s) << 16); }

// ---------------- weight permute+convert (f32 -> bf16), once per launch; also zeroes rms accum ----------------
// Packed channel order: n = role*384 + h*48 + e.  Source col:
//   values path: e<32 -> W_vqk col 24e+3h+role (normalized part); e>=32 -> W_vv col 24e+3h+role-768
//   coords path: role in {0,1} -> W_cqk col 16e+2h+role
__global__ __launch_bounds__(256) void wprep_k(
    const float* __restrict__ W_vqk, const float* __restrict__ W_vv, const float* __restrict__ W_cqk,
    const float* __restrict__ W_ov,  const float* __restrict__ b_vqk, const float* __restrict__ b_vv,
    const float* __restrict__ b_cqk, const float* __restrict__ g_vqk, const float* __restrict__ g_cqk,
    bf16* __restrict__ W1Tp, bf16* __restrict__ WcTp, bf16* __restrict__ WoT,
    float* __restrict__ bP0, float* __restrict__ bPc, float* __restrict__ gvP, float* __restrict__ gcP,
    float* __restrict__ rs_v, float* __restrict__ rs_c)
{
  int idx = blockIdx.x*256 + threadIdx.x;
  if (idx < 442368) {                     // W1Tp [1152][384]
    int n = idx/384, k = idx - n*384;
    int role = n/384, rem = n - role*384, h = rem/48, e = rem - (rem/48)*48;
    int c = 24*e + 3*h + role;
    float v = (e < 32) ? W_vqk[k*768 + c] : W_vv[k*384 + (c - 768)];
    W1Tp[n*384 + k] = tob(v);
  } else if (idx < 540672) {              // WcTp [768][128]
    int q = idx - 442368;
    int n = q >> 7, k = q & 127;
    int role = n/384, rem = n - role*384, h = rem/48, e = rem - (rem/48)*48;
    WcTp[n*128 + k] = tob(W_cqk[k*768 + 16*e + 2*h + role]);
  } else if (idx < 688128) {              // WoT [384][384]
    int q = idx - 540672;
    int n = q/384, k = q - n*384;
    WoT[n*384 + k] = tob(W_ov[k*384 + n]);
  } else if (idx < 689280) {              // bP0 [1152]
    int n = idx - 688128;
    int role = n/384, rem = n - role*384, h = rem/48, e = rem - (rem/48)*48;
    int c = 24*e + 3*h + role;
    bP0[n] = (e < 32) ? b_vqk[c] : b_vv[c - 768];
  } else if (idx < 690048) {              // bPc [768]
    int n = idx - 689280;
    int role = n/384, rem = n - role*384, h = rem/48, e = rem - (rem/48)*48;
    bPc[n] = b_cqk[16*e + 2*h + role];
  } else if (idx < 691200) {              // gvP [1152]: 1.0 for raw (e>=32) channels
    int n = idx - 690048;
    int role = n/384, rem = n - role*384, h = rem/48, e = rem - (rem/48)*48;
    gvP[n] = (e < 32) ? g_vqk[24*e + 3*h + role] : 1.0f;
  } else if (idx < 691968) {              // gcP [768]
    int n = idx - 691200;
    int role = n/384, rem = n - role*384, h = rem/48, e = rem - (rem/48)*48;
    gcP[n] = g_cqk[16*e + 2*h + role];
  } else if (idx < 716544) {              // zero rms accumulators for chunk 0
    int q = idx - 691968;
    if (q < CPIX) rs_v[q] = 0.f; else rs_c[q - CPIX] = 0.f;
  }
}

// ---------------- MFMA GEMM ----------------
// Grid: (row-tiles, col-tiles).  blockIdx.x = row-tile (fast dim; 96/192 % 8 == 0 so all col-tiles
// of one A row-panel land on the SAME XCD -> A fetched ~once per panel from HBM).
// MODE 0: roll-gather(values f32)[CPIX][384] @ W1Tp -> Y0 [CPIX][1152] bf16 (+bias), grid (96,9); rsum += qk v^2
// MODE 1: roll-gather(coords f32)[CPIX][128] @ WcTp -> Yc [CPIX][768]  bf16 (+bias), grid (96,6); rsum += v^2
// MODE 2: y_att bf16 [CPIX][384] @ WoT -> out f32 (+bias), grid (192,3), 64-row tiles; zeroes rms for next chunk
// MODE 0/1 epilogue: C-tile repacked through As/Bs LDS -> 128B-contiguous uint4 stores
// (fixes the 2.3x HBM write amplification of per-lane 2B scattered bf16 stores, seen in r6 rocprof).
template<int MODE>
__global__ __launch_bounds__(256,4) void gemm_k(const float* __restrict__ Af, const bf16* __restrict__ Ab,
    const bf16* __restrict__ WT, const float* __restrict__ biasP,
    bf16* __restrict__ outb, float* __restrict__ outf, float* __restrict__ rsum,
    float* __restrict__ z0, float* __restrict__ z1, int bb, int hf, int pix0)
{
  constexpr int KTOT = (MODE==1) ? 128 : 384;
  constexpr int NT   = (MODE==0) ? 1152 : (MODE==1) ? 768 : 384;
  constexpr int BM   = (MODE==2) ? 64 : 128;   // rows per block
  constexpr int MT4  = BM/32;                  // 16-row tiles per wave
  constexpr int ACH  = BM*8;                   // A-tile 8-elem chunks per K-step
  __shared__ bf16 As[128][72];      // +8 pad: 2-way-max bank aliasing on b128 reads
  __shared__ bf16 Bs[128][72];
  const int tid = threadIdx.x, lane = tid & 63, wid = tid >> 6;
  const int wr = (wid >> 1)*(BM/2), wc = (wid & 1)*64;   // 2x2 waves
  const int rowbase = blockIdx.x*BM;
  const int nbase   = blockIdx.y*128;

  if constexpr (MODE == 2) {        // zero rms accumulators for the NEXT chunk (stream-ordered)
    if (blockIdx.y == 0) {
      if (tid < 64) z0[rowbase + tid] = 0.f;
      else if (tid < 128) z1[rowbase + tid - 64] = 0.f;
    }
  }

  f32x4 acc[MT4][4] = {};
  for (int ks = 0; ks < KTOT; ks += 64) {
    __syncthreads();
    #pragma unroll
    for (int it = 0; it < (ACH + 1024)/256; it++) {
      int idx = it*256 + tid;
      if (idx < ACH) {
        int r = idx >> 3, c = idx & 7;
        if constexpr (MODE == 2) {
          *(uint4*)&As[r][c*8] = *(const uint4*)(Ab + (size_t)(rowbase + r)*KTOT + ks + c*8);
        } else {
          // fused rolled gather + f32->bf16: pixel raster -> rolled source pixel
          int pix = rowbase + r;
          int lr = pix/192, lc = pix - (pix/192)*192;
          int srow = (hf*64 + lr + 4) % 192;     // jnp.roll(t,-4)
          int scol = (lc + 4) % 192;
          const float* src = Af + (((size_t)bb*192 + srow)*192 + scol)*KTOT + ks + c*8;
          float4 f0 = *(const float4*)src;
          float4 f1 = *(const float4*)(src + 4);
          union { bf16 h[8]; uint4 u4; } t;
          t.h[0]=tob(f0.x); t.h[1]=tob(f0.y); t.h[2]=tob(f0.z); t.h[3]=tob(f0.w);
          t.h[4]=tob(f1.x); t.h[5]=tob(f1.y); t.h[6]=tob(f1.z); t.h[7]=tob(f1.w);
          *(uint4*)&As[r][c*8] = t.u4;
        }
      } else {
        int q = idx - ACH; int r = q >> 3, c = q & 7;
        *(uint4*)&Bs[r][c*8] = *(const uint4*)(WT + (size_t)(nbase + r)*KTOT + ks + c*8);
      }
    }
    __syncthreads();
    #pragma unroll
    for (int k2 = 0; k2 < 64; k2 += 32) {
      const int kb = k2 + (lane >> 4)*8, ml = lane & 15;
      bf16x8 a[MT4], b[4];
      #pragma unroll
      for (int t = 0; t < MT4; t++) a[t] = *(const bf16x8*)&As[wr + t*16 + ml][kb];
      #pragma unroll
      for (int t = 0; t < 4; t++)  b[t] = *(const bf16x8*)&Bs[wc + t*16 + ml][kb];
      #pragma unroll
      for (int mt = 0; mt < MT4; mt++)
      #pragma unroll
      for (int nt = 0; nt < 4; nt++)
        acc[mt][nt] = __builtin_amdgcn_mfma_f32_16x16x32_bf16(a[mt], b[nt], acc[mt][nt], 0, 0, 0);
    }
  }
  // epilogue: C/D layout col=lane&15, row=(lane>>4)*4+reg
  const int lr4 = (lane >> 4)*4, lcol = lane & 15;
  if constexpr (MODE == 2) {
    #pragma unroll
    for (int mt = 0; mt < MT4; mt++)
    #pragma unroll
    for (int nt = 0; nt < 4; nt++) {
      f32x4 av = acc[mt][nt];
      int n = nbase + wc + nt*16 + lcol;
      float bv = biasP[n];
      #pragma unroll
      for (int i = 0; i < 4; i++) {
        int pix = rowbase + wr + mt*16 + lr4 + i;
        outf[(size_t)(pix0 + pix)*384 + n] = av[i] + bv;
      }
    }
  } else {
    // bias + rms partials (register-side, unchanged math), C repacked into LDS:
    // wc==0 waves -> As as C[rows][cols 0..63], wc==64 waves -> Bs as C[rows][cols 64..127]
    __syncthreads();                      // all waves done reading As/Bs for MFMA
    bf16* Crow = (wc == 0) ? &As[0][0] : &Bs[0][0];
    #pragma unroll
    for (int mt = 0; mt < MT4; mt++) {
      #pragma unroll
      for (int i = 0; i < 4; i++) {
        int row = wr + mt*16 + lr4 + i;
        int pix = rowbase + row;
        float sq_ = 0.f;
        #pragma unroll
        for (int nt = 0; nt < 4; nt++) {
          int n = nbase + wc + nt*16 + lcol;
          float v = acc[mt][nt][i] + biasP[n];
          Crow[row*72 + nt*16 + lcol] = tob(v);
          if (MODE == 1 || (n % 48) < 32) sq_ += v*v;   // qk-normalized channels only (MODE 0)
        }
        sq_ += __shfl_xor(sq_, 1); sq_ += __shfl_xor(sq_, 2);
        sq_ += __shfl_xor(sq_, 4); sq_ += __shfl_xor(sq_, 8);
        if (lcol == 0) atomicAdd(&rsum[pix], sq_);
      }
    }
    __syncthreads();
    // cooperative coalesced store: per row, 128 cols x 2B = 256B as 2 halves of 128B;
    // 2048 uint4 units -> 8 per thread; every segment 128B-contiguous & 256B-aligned.
    #pragma unroll
    for (int u = 0; u < 8; u++) {
      int q = u*256 + tid;
      int half = q >> 10, idx = q & 1023, r = idx >> 3, s = idx & 7;
      const bf16* srcp = half ? &Bs[r][s*8] : &As[r][s*8];
      *(uint4*)(outb + (size_t)(rowbase + r)*NT + nbase + half*64 + s*8) = *(const uint4*)srcp;
    }
  }
}

// ---------------- helpers for MFMA attention ----------------
__device__ __forceinline__ bf16x8 pack8g(uint4 raw, float r, float4 ga, float4 gb)
{
  union { uint4 u4; unsigned short us[8]; } rw; rw.u4 = raw;
  union { bf16x8 v; bf16 h[8]; } o;
  o.h[0] = tob(bf2f((short)rw.us[0]) * (r * ga.x));
  o.h[1] = tob(bf2f((short)rw.us[1]) * (r * ga.y));
  o.h[2] = tob(bf2f((short)rw.us[2]) * (r * ga.z));
  o.h[3] = tob(bf2f((short)rw.us[3]) * (r * ga.w));
  o.h[4] = tob(bf2f((short)rw.us[4]) * (r * gb.x));
  o.h[5] = tob(bf2f((short)rw.us[5]) * (r * gb.y));
  o.h[6] = tob(bf2f((short)rw.us[6]) * (r * gb.z));
  o.h[7] = tob(bf2f((short)rw.us[7]) * (r * gb.w));
  return o.v;
}

__device__ __forceinline__ float rmsf(float s){ return rsqrtf(s*(1.f/768.f) + 1e-6f); }

// ---------------- windowed attention via MFMA: block per (window, head) ----------------
// 4 waves row-split (16 S-rows each). QK^T: A-frag (Q) loaded direct from global into regs
// (scaled q' in bf16), B-frag (K') from LDS.  Softmax fully in-register (row lives in a
// 16-lane group).  P (bf16, un-normalized exp) through LDS only for the PV A-fragment;
// V staged transposed; 1/rowsum applied to PV output.  rms = rsqrt computed inline from raw sums.
__global__ __launch_bounds__(256,4) void attn_k(const bf16* __restrict__ Y0, const bf16* __restrict__ Yc,
    const float* __restrict__ rs_v, const float* __restrict__ rs_c,
    const float* __restrict__ gvP, const float* __restrict__ gcP,
    const float* __restrict__ lam_p, const float* __restrict__ pos,
    bf16* __restrict__ y_att, int hf)
{
  __shared__ bf16 Ks[64][104];     // k' rows [j][96], +8 pad (208B stride, 16B-mult)
  __shared__ bf16 Vt[48][72];      // v' transposed [e][64], +8 pad
  __shared__ bf16 Pb[64][72];      // P bf16 (per-wave-private rows); reused for O repack
  __shared__ float sq[96];         // q channel scale: g*SCL (values) / g*lam*SCL (coords)
  __shared__ float poss[225];      // rel-pos bias table 15x15
  const int tid = threadIdx.x, lane = tid & 63, w = tid >> 6;
  const int win = blockIdx.x, h = blockIdx.y;
  const int wx = win/24, wy = win - (win/24)*24;
  const float lam = lam_p[0];
  const float SCL = 0.14433756729740643f;   // 1/sqrt(48)

  if (tid < 96) sq[tid] = (tid < 48 ? gvP[h*48 + tid] : gcP[h*48 + tid - 48]*lam) * SCL;
  if (tid < 225) poss[tid] = pos[tid];

  // ---- stage K' (values+coords) and V' (transposed), 18 wave-uniform groups ----
  {
    const int j = lane;
    const int p = (wx*8 + (j>>3))*192 + wy*8 + (j&7);
    const float rvj = rmsf(rs_v[p]), rcj = rmsf(rs_c[p]);
    for (int grp = w; grp < 18; grp += 4) {
      if (grp < 6) {                        // K values part: e = c*8..c*8+7
        int c = grp;
        uint4 raw = *(const uint4*)(Y0 + (size_t)p*1152 + 384 + h*48 + c*8);
        const float* gp = gvP + 384 + h*48 + c*8;
        float4 ga = *(const float4*)gp, gb = *(const float4*)(gp+4);
        float r = (c < 4) ? rvj : 1.0f;     // e<32 normalized, e>=32 raw
        union { bf16x8 v; uint4 u4; } o; o.v = pack8g(raw, r, ga, gb);
        *(uint4*)&Ks[j][c*8] = o.u4;
      } else if (grp < 12) {                // K coords part -> k' cols 48..95
        int c = grp - 6;
        uint4 raw = *(const uint4*)(Yc + (size_t)p*768 + 384 + h*48 + c*8);
        const float* gp = gcP + 384 + h*48 + c*8;
        float4 ga = *(const float4*)gp, gb = *(const float4*)(gp+4);
        union { bf16x8 v; uint4 u4; } o; o.v = pack8g(raw, rcj, ga, gb);
        *(uint4*)&Ks[j][48 + c*8] = o.u4;
      } else {                              // V -> transposed Vt[e][j]
        int c = grp - 12;
        uint4 raw = *(const uint4*)(Y0 + (size_t)p*1152 + 768 + h*48 + c*8);
        const float* gp = gvP + 768 + h*48 + c*8;
        float4 ga = *(const float4*)gp, gb = *(const float4*)(gp+4);
        float r = (c < 4) ? rvj : 1.0f;
        union { uint4 u4; unsigned short us[8]; } rw; rw.u4 = raw;
        Vt[c*8+0][j] = tob(bf2f((short)rw.us[0]) * (r * ga.x));
        Vt[c*8+1][j] = tob(bf2f((short)rw.us[1]) * (r * ga.y));
        Vt[c*8+2][j] = tob(bf2f((short)rw.us[2]) * (r * ga.z));
        Vt[c*8+3][j] = tob(bf2f((short)rw.us[3]) * (r * ga.w));
        Vt[c*8+4][j] = tob(bf2f((short)rw.us[4]) * (r * gb.x));
        Vt[c*8+5][j] = tob(bf2f((short)rw.us[5]) * (r * gb.y));
        Vt[c*8+6][j] = tob(bf2f((short)rw.us[6]) * (r * gb.z));
        Vt[c*8+7][j] = tob(bf2f((short)rw.us[7]) * (r * gb.w));
      }
    }
  }
  __syncthreads();                          // the only block-wide barrier

  // ---- Q fragments direct from global (A-frag: row = lane&15, k = (lane>>4)*8 + kb) ----
  const int ml = lane & 15, k0 = (lane >> 4)*8;
  const int mrow = w*16 + ml;
  const int pA = (wx*8 + (mrow>>3))*192 + wy*8 + (mrow&7);
  const float rvA = rmsf(rs_v[pA]), rcA = rmsf(rs_c[pA]);
  bf16x8 qf0, qf1, qf2;
  {
    uint4 r0 = *(const uint4*)(Y0 + (size_t)pA*1152 + h*48 + k0);            // k in [0,32): values, rms
    float4 ga = *(const float4*)&sq[k0],      gb = *(const float4*)&sq[k0+4];
    qf0 = pack8g(r0, rvA, ga, gb);
    const bf16* s1 = (k0 < 16) ? (Y0 + (size_t)pA*1152 + h*48 + 32 + k0)     // k in [32,48): values raw
                               : (Yc + (size_t)pA*768  + h*48 + (k0 - 16));  // k in [48,64): coords
    float r1 = (k0 < 16) ? 1.0f : rcA;
    uint4 raw1 = *(const uint4*)s1;
    ga = *(const float4*)&sq[32+k0]; gb = *(const float4*)&sq[36+k0];
    qf1 = pack8g(raw1, r1, ga, gb);
    uint4 r2 = *(const uint4*)(Yc + (size_t)pA*768 + h*48 + 16 + k0);        // k in [64,96): coords
    ga = *(const float4*)&sq[64+k0]; gb = *(const float4*)&sq[68+k0];
    qf2 = pack8g(r2, rcA, ga, gb);
  }

  // ---- QK^T: wave w covers S rows [w*16, w*16+16), all 64 cols, K=96 ----
  f32x4 acc[4] = {};
  #pragma unroll
  for (int nt = 0; nt < 4; nt++) {
    bf16x8 b0 = *(const bf16x8*)&Ks[nt*16 + ml][k0];
    bf16x8 b1 = *(const bf16x8*)&Ks[nt*16 + ml][32 + k0];
    bf16x8 b2 = *(const bf16x8*)&Ks[nt*16 + ml][64 + k0];
    acc[nt] = __builtin_amdgcn_mfma_f32_16x16x32_bf16(qf0, b0, acc[nt], 0, 0, 0);
    acc[nt] = __builtin_amdgcn_mfma_f32_16x16x32_bf16(qf1, b1, acc[nt], 0, 0, 0);
    acc[nt] = __builtin_amdgcn_mfma_f32_16x16x32_bf16(qf2, b2, acc[nt], 0, 0, 0);
  }

  // ---- bias + mask + in-register softmax (row = 16-lane group, 4 regs x 4 col-tiles) ----
  const bool rowm = (hf == 2) && (wx == 7);
  const bool colm = (wy == 23);
  const int g4 = (lane >> 4)*4;
  float pv[4][4];
  float inv_[4];
  #pragma unroll
  for (int i = 0; i < 4; i++) {
    int r = w*16 + g4 + i;
    int txi = r >> 3, tyi = r & 7;
    #pragma unroll
    for (int nt = 0; nt < 4; nt++) {
      int j = nt*16 + ml;
      int txj = j >> 3, tyj = j & 7;
      float v = acc[nt][i] + poss[(txj - txi + 7)*15 + (tyj - tyi + 7)];
      if ((rowm && ((txi >= 4) != (txj >= 4))) || (colm && ((tyi >= 4) != (tyj >= 4)))) v = -1e30f;
      pv[i][nt] = v;
    }
    float mx = fmaxf(fmaxf(pv[i][0], pv[i][1]), fmaxf(pv[i][2], pv[i][3]));
    #pragma unroll
    for (int m = 1; m < 16; m <<= 1) mx = fmaxf(mx, __shfl_xor(mx, m));
    float s0 = 0.f;
    #pragma unroll
    for (int nt = 0; nt < 4; nt++) { pv[i][nt] = __expf(pv[i][nt] - mx); s0 += pv[i][nt]; }
    #pragma unroll
    for (int m = 1; m < 16; m <<= 1) s0 += __shfl_xor(s0, m);
    inv_[i] = 1.f / s0;
  }
  #pragma unroll
  for (int i = 0; i < 4; i++)
  #pragma unroll
  for (int nt = 0; nt < 4; nt++)
    Pb[w*16 + g4 + i][nt*16 + ml] = tob(pv[i][nt]);   // un-normalized; 1/sum folded into O

  // ---- PV: O[16x48] per wave, K=64.  A = Pb (own rows), B = Vt (transposed V) ----
  f32x4 o0 = {}, o1 = {}, o2 = {};
  {
    bf16x8 a0 = *(const bf16x8*)&Pb[w*16 + ml][k0];
    bf16x8 b;
    b = *(const bf16x8*)&Vt[ 0 + ml][k0];      o0 = __builtin_amdgcn_mfma_f32_16x16x32_bf16(a0, b, o0, 0, 0, 0);
    b = *(const bf16x8*)&Vt[16 + ml][k0];      o1 = __builtin_amdgcn_mfma_f32_16x16x32_bf16(a0, b, o1, 0, 0, 0);
    b = *(const bf16x8*)&Vt[32 + ml][k0];      o2 = __builtin_amdgcn_mfma_f32_16x16x32_bf16(a0, b, o2, 0, 0, 0);
    bf16x8 a1 = *(const bf16x8*)&Pb[w*16 + ml][32 + k0];
    b = *(const bf16x8*)&Vt[ 0 + ml][32 + k0]; o0 = __builtin_amdgcn_mfma_f32_16x16x32_bf16(a1, b, o0, 0, 0, 0);
    b = *(const bf16x8*)&Vt[16 + ml][32 + k0]; o1 = __builtin_amdgcn_mfma_f32_16x16x32_bf16(a1, b, o1, 0, 0, 0);
    b = *(const bf16x8*)&Vt[32 + ml][32 + k0]; o2 = __builtin_amdgcn_mfma_f32_16x16x32_bf16(a1, b, o2, 0, 0, 0);
  }

  // ---- O repack into Pb (own rows, wave-private) then vectorized global store ----
  #pragma unroll
  for (int i = 0; i < 4; i++) {
    Pb[w*16 + g4 + i][     ml] = tob(o0[i] * inv_[i]);
    Pb[w*16 + g4 + i][16 + ml] = tob(o1[i] * inv_[i]);
    Pb[w*16 + g4 + i][32 + ml] = tob(o2[i] * inv_[i]);
  }
  #pragma unroll
  for (int s2 = 0; s2 < 3; s2++) {
    int u = s2*64 + lane;                 // 192 units: 16 rows x 12 uint2-segments
    int row = u / 12, seg = u - row*12;
    int rr = w*16 + row;
    int pC = (wx*8 + (rr>>3))*192 + wy*8 + (rr&7);
    uint2 d = *(const uint2*)&Pb[rr][seg*4];
    *(uint2*)(y_att + (size_t)pC*384 + h*48 + seg*4) = d;
  }
}

extern "C" void kernel_launch(void* const* d_in, const int* in_sizes, int n_in,
                              void* d_out, int out_size, void* d_ws, size_t ws_size,
                              hipStream_t stream)
{
  const float* values = (const float*)d_in[0];
  const float* coords = (const float*)d_in[1];
  const float* W_vqk  = (const float*)d_in[2];
  const float* b_vqk  = (const float*)d_in[3];
  const float* g_vqk  = (const float*)d_in[4];
  const float* W_vv   = (const float*)d_in[5];
  const float* b_vv   = (const float*)d_in[6];
  const float* W_cqk  = (const float*)d_in[7];
  const float* b_cqk  = (const float*)d_in[8];
  const float* g_cqk  = (const float*)d_in[9];
  const float* lam    = (const float*)d_in[10];
  const float* pos    = (const float*)d_in[11];
  const float* W_ov   = (const float*)d_in[12];
  const float* b_ov   = (const float*)d_in[13];
  float* out = (float*)d_out;

  char* ws = (char*)d_ws;
  bf16*  W1Tp  = (bf16*)(ws + 0);           // 1152*384*2   = 884736
  bf16*  WcTp  = (bf16*)(ws + 884736);      // 768*128*2    = 196608
  bf16*  WoT   = (bf16*)(ws + 1081344);     // 384*384*2    = 294912
  float* bP0   = (float*)(ws + 1376256);    // 1152*4
  float* bPc   = (float*)(ws + 1380864);    // 768*4
  float* gvP   = (float*)(ws + 1383936);    // 1152*4
  float* gcP   = (float*)(ws + 1388544);    // 768*4
  bf16*  Y0    = (bf16*)(ws + 1391616);     // CPIX*1152*2  = 28311552
  bf16*  Yc    = (bf16*)(ws + 29703168);    // CPIX*768*2   = 18874368
  float* rs_v  = (float*)(ws + 48577536);   // CPIX*4  (raw sum-of-squares accumulators)
  float* rs_c  = (float*)(ws + 48626688);   // CPIX*4
  bf16*  y_att = (bf16*)(ws + 48675840);    // CPIX*384*2   = 9437184 -> total 58113024
  (void)ws_size; (void)in_sizes; (void)n_in; (void)out_size;

  wprep_k<<<2799, 256, 0, stream>>>(W_vqk, W_vv, W_cqk, W_ov, b_vqk, b_vv, b_cqk, g_vqk, g_cqk,
                                    W1Tp, WcTp, WoT, bP0, bPc, gvP, gcP, rs_v, rs_c);

  for (int ch = 0; ch < 6; ch++) {
    int bb = ch/3, hf = ch - bb*3;
    gemm_k<0><<<dim3(96,9), 256, 0, stream>>>(values, nullptr, W1Tp, bP0, Y0, nullptr, rs_v,
                                              nullptr, nullptr, bb, hf, 0);
    gemm_k<1><<<dim3(96,6), 256, 0, stream>>>(coords, nullptr, WcTp, bPc, Yc, nullptr, rs_c,
                                              nullptr, nullptr, bb, hf, 0);
    attn_k<<<dim3(192,8), 256, 0, stream>>>(Y0, Yc, rs_v, rs_c, gvP, gcP, lam, pos, y_att, hf);
    gemm_k<2><<<dim3(192,3), 256, 0, stream>>>(nullptr, y_att, WoT, b_ov, nullptr, out, nullptr,
                                               rs_v, rs_c, 0, 0, ch*CPIX);
  }
}

// Round 8
// 608.516 us; speedup vs baseline: 1.4126x; 1.1364x over previous
//
#include <hip/hip_runtime.h>
#include <hip/hip_bf16.h>

typedef __hip_bfloat16 bf16;
typedef __attribute__((ext_vector_type(8))) short bf16x8;
typedef __attribute__((ext_vector_type(4))) float f32x4;

__device__ __forceinline__ float tof(bf16 x){ return __bfloat162float(x); }
__device__ __forceinline__ bf16  tob(float x){ return __float2bfloat16(x); }
__device__ __forceinline__ float bf2f(short s){ return __uint_as_float(((unsigned)(unsigned short)s) << 16); }

// ---------------- weight permute+convert (f32 -> bf16), once per launch; also zeroes rms accum ----------------
// Packed channel order: n = role*384 + h*48 + e.  Source col:
//   values path: e<32 -> W_vqk col 24e+3h+role (normalized part); e>=32 -> W_vv col 24e+3h+role-768
//   coords path: role in {0,1} -> W_cqk col 16e+2h+role
__global__ __launch_bounds__(256) void wprep_k(
    const float* __restrict__ W_vqk, const float* __restrict__ W_vv, const float* __restrict__ W_cqk,
    const float* __restrict__ W_ov,  const float* __restrict__ b_vqk, const float* __restrict__ b_vv,
    const float* __restrict__ b_cqk, const float* __restrict__ g_vqk, const float* __restrict__ g_cqk,
    bf16* __restrict__ W1Tp, bf16* __restrict__ WcTp, bf16* __restrict__ WoT,
    float* __restrict__ bP0, float* __restrict__ bPc, float* __restrict__ gvP, float* __restrict__ gcP,
    float* __restrict__ rs_v, float* __restrict__ rs_c, int npix)
{
  int idx = blockIdx.x*256 + threadIdx.x;
  if (idx < 442368) {                     // W1Tp [1152][384]
    int n = idx/384, k = idx - n*384;
    int role = n/384, rem = n - role*384, h = rem/48, e = rem - (rem/48)*48;
    int c = 24*e + 3*h + role;
    float v = (e < 32) ? W_vqk[k*768 + c] : W_vv[k*384 + (c - 768)];
    W1Tp[n*384 + k] = tob(v);
  } else if (idx < 540672) {              // WcTp [768][128]
    int q = idx - 442368;
    int n = q >> 7, k = q & 127;
    int role = n/384, rem = n - role*384, h = rem/48, e = rem - (rem/48)*48;
    WcTp[n*128 + k] = tob(W_cqk[k*768 + 16*e + 2*h + role]);
  } else if (idx < 688128) {              // WoT [384][384]
    int q = idx - 540672;
    int n = q/384, k = q - n*384;
    WoT[n*384 + k] = tob(W_ov[k*384 + n]);
  } else if (idx < 689280) {              // bP0 [1152]
    int n = idx - 688128;
    int role = n/384, rem = n - role*384, h = rem/48, e = rem - (rem/48)*48;
    int c = 24*e + 3*h + role;
    bP0[n] = (e < 32) ? b_vqk[c] : b_vv[c - 768];
  } else if (idx < 690048) {              // bPc [768]
    int n = idx - 689280;
    int role = n/384, rem = n - role*384, h = rem/48, e = rem - (rem/48)*48;
    bPc[n] = b_cqk[16*e + 2*h + role];
  } else if (idx < 691200) {              // gvP [1152]: 1.0 for raw (e>=32) channels
    int n = idx - 690048;
    int role = n/384, rem = n - role*384, h = rem/48, e = rem - (rem/48)*48;
    gvP[n] = (e < 32) ? g_vqk[24*e + 3*h + role] : 1.0f;
  } else if (idx < 691968) {              // gcP [768]
    int n = idx - 691200;
    int role = n/384, rem = n - role*384, h = rem/48, e = rem - (rem/48)*48;
    gcP[n] = g_cqk[16*e + 2*h + role];
  } else if (idx < 691968 + 2*npix) {     // zero rms accumulators for the first region
    int q = idx - 691968;
    if (q < npix) rs_v[q] = 0.f; else rs_c[q - npix] = 0.f;
  }
}

// ---------------- MFMA GEMM (region = nrows x 192 pixels of one batch, local pixel indexing) ------
// MODE 0: roll-gather(values f32)[npix][384] @ W1Tp -> Y0 [npix][1152] bf16 (+bias); rsum += qk v^2
// MODE 1: roll-gather(coords f32)[npix][128] @ WcTp -> Yc [npix][768]  bf16 (+bias); rsum += v^2
// MODE 2: y_att bf16 [npix][384] @ WoT -> out f32 (+bias), 64-row tiles; zeroes rms for next region
// blockIdx.x = row-tile (fast dim, multiple of 8) -> col-tiles of one A-panel share an XCD.
// MODE 0/1 epilogue: C repacked through As/Bs -> 128B-contiguous uint4 stores.
template<int MODE>
__global__ __launch_bounds__(256,4) void gemm_k(const float* __restrict__ Af, const bf16* __restrict__ Ab,
    const bf16* __restrict__ WT, const float* __restrict__ biasP,
    bf16* __restrict__ outb, float* __restrict__ outf, float* __restrict__ rsum,
    float* __restrict__ z0, float* __restrict__ z1, int bb, int row0, int pix0)
{
  constexpr int KTOT = (MODE==1) ? 128 : 384;
  constexpr int NT   = (MODE==0) ? 1152 : (MODE==1) ? 768 : 384;
  constexpr int BM   = (MODE==2) ? 64 : 128;   // rows per block
  constexpr int MT4  = BM/32;                  // 16-row tiles per wave
  constexpr int ACH  = BM*8;                   // A-tile 8-elem chunks per K-step
  __shared__ bf16 As[128][72];      // +8 pad: 2-way-max bank aliasing on b128 reads
  __shared__ bf16 Bs[128][72];
  const int tid = threadIdx.x, lane = tid & 63, wid = tid >> 6;
  const int wr = (wid >> 1)*(BM/2), wc = (wid & 1)*64;   // 2x2 waves
  const int rowbase = blockIdx.x*BM;
  const int nbase   = blockIdx.y*128;

  if constexpr (MODE == 2) {        // zero rms accumulators for the NEXT region (stream-ordered)
    if (blockIdx.y == 0) {
      if (tid < 64) z0[rowbase + tid] = 0.f;
      else if (tid < 128) z1[rowbase + tid - 64] = 0.f;
    }
  }

  f32x4 acc[MT4][4] = {};
  for (int ks = 0; ks < KTOT; ks += 64) {
    __syncthreads();
    #pragma unroll
    for (int it = 0; it < (ACH + 1024)/256; it++) {
      int idx = it*256 + tid;
      if (idx < ACH) {
        int r = idx >> 3, c = idx & 7;
        if constexpr (MODE == 2) {
          *(uint4*)&As[r][c*8] = *(const uint4*)(Ab + (size_t)(rowbase + r)*KTOT + ks + c*8);
        } else {
          // fused rolled gather + f32->bf16: local pixel -> rolled source pixel
          int pix = rowbase + r;
          int lr = pix/192, lc = pix - (pix/192)*192;
          int srow = (row0 + lr + 4) % 192;      // jnp.roll(t,-4)
          int scol = (lc + 4) % 192;
          const float* src = Af + (((size_t)bb*192 + srow)*192 + scol)*KTOT + ks + c*8;
          float4 f0 = *(const float4*)src;
          float4 f1 = *(const float4*)(src + 4);
          union { bf16 h[8]; uint4 u4; } t;
          t.h[0]=tob(f0.x); t.h[1]=tob(f0.y); t.h[2]=tob(f0.z); t.h[3]=tob(f0.w);
          t.h[4]=tob(f1.x); t.h[5]=tob(f1.y); t.h[6]=tob(f1.z); t.h[7]=tob(f1.w);
          *(uint4*)&As[r][c*8] = t.u4;
        }
      } else {
        int q = idx - ACH; int r = q >> 3, c = q & 7;
        *(uint4*)&Bs[r][c*8] = *(const uint4*)(WT + (size_t)(nbase + r)*KTOT + ks + c*8);
      }
    }
    __syncthreads();
    #pragma unroll
    for (int k2 = 0; k2 < 64; k2 += 32) {
      const int kb = k2 + (lane >> 4)*8, ml = lane & 15;
      bf16x8 a[MT4], b[4];
      #pragma unroll
      for (int t = 0; t < MT4; t++) a[t] = *(const bf16x8*)&As[wr + t*16 + ml][kb];
      #pragma unroll
      for (int t = 0; t < 4; t++)  b[t] = *(const bf16x8*)&Bs[wc + t*16 + ml][kb];
      #pragma unroll
      for (int mt = 0; mt < MT4; mt++)
      #pragma unroll
      for (int nt = 0; nt < 4; nt++)
        acc[mt][nt] = __builtin_amdgcn_mfma_f32_16x16x32_bf16(a[mt], b[nt], acc[mt][nt], 0, 0, 0);
    }
  }
  // epilogue: C/D layout col=lane&15, row=(lane>>4)*4+reg
  const int lr4 = (lane >> 4)*4, lcol = lane & 15;
  if constexpr (MODE == 2) {
    #pragma unroll
    for (int mt = 0; mt < MT4; mt++)
    #pragma unroll
    for (int nt = 0; nt < 4; nt++) {
      f32x4 av = acc[mt][nt];
      int n = nbase + wc + nt*16 + lcol;
      float bv = biasP[n];
      #pragma unroll
      for (int i = 0; i < 4; i++) {
        int pix = rowbase + wr + mt*16 + lr4 + i;
        outf[(size_t)(pix0 + pix)*384 + n] = av[i] + bv;
      }
    }
  } else {
    // bias + rms partials (register-side), C repacked into LDS for coalesced stores
    __syncthreads();                      // all waves done reading As/Bs for MFMA
    bf16* Crow = (wc == 0) ? &As[0][0] : &Bs[0][0];
    #pragma unroll
    for (int mt = 0; mt < MT4; mt++) {
      #pragma unroll
      for (int i = 0; i < 4; i++) {
        int row = wr + mt*16 + lr4 + i;
        int pix = rowbase + row;
        float sq_ = 0.f;
        #pragma unroll
        for (int nt = 0; nt < 4; nt++) {
          int n = nbase + wc + nt*16 + lcol;
          float v = acc[mt][nt][i] + biasP[n];
          Crow[row*72 + nt*16 + lcol] = tob(v);
          if (MODE == 1 || (n % 48) < 32) sq_ += v*v;   // qk-normalized channels only (MODE 0)
        }
        sq_ += __shfl_xor(sq_, 1); sq_ += __shfl_xor(sq_, 2);
        sq_ += __shfl_xor(sq_, 4); sq_ += __shfl_xor(sq_, 8);
        if (lcol == 0) atomicAdd(&rsum[pix], sq_);
      }
    }
    __syncthreads();
    #pragma unroll
    for (int u = 0; u < 8; u++) {
      int q = u*256 + tid;
      int half = q >> 10, idx = q & 1023, r = idx >> 3, s = idx & 7;
      const bf16* srcp = half ? &Bs[r][s*8] : &As[r][s*8];
      *(uint4*)(outb + (size_t)(rowbase + r)*NT + nbase + half*64 + s*8) = *(const uint4*)srcp;
    }
  }
}

// ---------------- helpers for MFMA attention ----------------
__device__ __forceinline__ bf16x8 pack8g(uint4 raw, float r, float4 ga, float4 gb)
{
  union { uint4 u4; unsigned short us[8]; } rw; rw.u4 = raw;
  union { bf16x8 v; bf16 h[8]; } o;
  o.h[0] = tob(bf2f((short)rw.us[0]) * (r * ga.x));
  o.h[1] = tob(bf2f((short)rw.us[1]) * (r * ga.y));
  o.h[2] = tob(bf2f((short)rw.us[2]) * (r * ga.z));
  o.h[3] = tob(bf2f((short)rw.us[3]) * (r * ga.w));
  o.h[4] = tob(bf2f((short)rw.us[4]) * (r * gb.x));
  o.h[5] = tob(bf2f((short)rw.us[5]) * (r * gb.y));
  o.h[6] = tob(bf2f((short)rw.us[6]) * (r * gb.z));
  o.h[7] = tob(bf2f((short)rw.us[7]) * (r * gb.w));
  return o.v;
}

__device__ __forceinline__ float rmsf(float s){ return rsqrtf(s*(1.f/768.f) + 1e-6f); }

// ---------------- windowed attention via MFMA: block per (window, head) ----------------
// grid.x = (nrows/8)*24 windows (local region), wx = win/24 window-row within region.
// rowm mask applies when GLOBAL window-row == 23: (row0/8 + wx) == 23.
__global__ __launch_bounds__(256,4) void attn_k(const bf16* __restrict__ Y0, const bf16* __restrict__ Yc,
    const float* __restrict__ rs_v, const float* __restrict__ rs_c,
    const float* __restrict__ gvP, const float* __restrict__ gcP,
    const float* __restrict__ lam_p, const float* __restrict__ pos,
    bf16* __restrict__ y_att, int row0)
{
  __shared__ bf16 Ks[64][104];     // k' rows [j][96], +8 pad (208B stride, 16B-mult)
  __shared__ bf16 Vt[48][72];      // v' transposed [e][64], +8 pad
  __shared__ bf16 Pb[64][72];      // P bf16 (per-wave-private rows); reused for O repack
  __shared__ float sq[96];         // q channel scale: g*SCL (values) / g*lam*SCL (coords)
  __shared__ float poss[225];      // rel-pos bias table 15x15
  const int tid = threadIdx.x, lane = tid & 63, w = tid >> 6;
  const int win = blockIdx.x, h = blockIdx.y;
  const int wx = win/24, wy = win - (win/24)*24;
  const float lam = lam_p[0];
  const float SCL = 0.14433756729740643f;   // 1/sqrt(48)

  if (tid < 96) sq[tid] = (tid < 48 ? gvP[h*48 + tid] : gcP[h*48 + tid - 48]*lam) * SCL;
  if (tid < 225) poss[tid] = pos[tid];

  // ---- stage K' (values+coords) and V' (transposed), 18 wave-uniform groups ----
  {
    const int j = lane;
    const int p = (wx*8 + (j>>3))*192 + wy*8 + (j&7);
    const float rvj = rmsf(rs_v[p]), rcj = rmsf(rs_c[p]);
    for (int grp = w; grp < 18; grp += 4) {
      if (grp < 6) {                        // K values part: e = c*8..c*8+7
        int c = grp;
        uint4 raw = *(const uint4*)(Y0 + (size_t)p*1152 + 384 + h*48 + c*8);
        const float* gp = gvP + 384 + h*48 + c*8;
        float4 ga = *(const float4*)gp, gb = *(const float4*)(gp+4);
        float r = (c < 4) ? rvj : 1.0f;     // e<32 normalized, e>=32 raw
        union { bf16x8 v; uint4 u4; } o; o.v = pack8g(raw, r, ga, gb);
        *(uint4*)&Ks[j][c*8] = o.u4;
      } else if (grp < 12) {                // K coords part -> k' cols 48..95
        int c = grp - 6;
        uint4 raw = *(const uint4*)(Yc + (size_t)p*768 + 384 + h*48 + c*8);
        const float* gp = gcP + 384 + h*48 + c*8;
        float4 ga = *(const float4*)gp, gb = *(const float4*)(gp+4);
        union { bf16x8 v; uint4 u4; } o; o.v = pack8g(raw, rcj, ga, gb);
        *(uint4*)&Ks[j][48 + c*8] = o.u4;
      } else {                              // V -> transposed Vt[e][j]
        int c = grp - 12;
        uint4 raw = *(const uint4*)(Y0 + (size_t)p*1152 + 768 + h*48 + c*8);
        const float* gp = gvP + 768 + h*48 + c*8;
        float4 ga = *(const float4*)gp, gb = *(const float4*)(gp+4);
        float r = (c < 4) ? rvj : 1.0f;
        union { uint4 u4; unsigned short us[8]; } rw; rw.u4 = raw;
        Vt[c*8+0][j] = tob(bf2f((short)rw.us[0]) * (r * ga.x));
        Vt[c*8+1][j] = tob(bf2f((short)rw.us[1]) * (r * ga.y));
        Vt[c*8+2][j] = tob(bf2f((short)rw.us[2]) * (r * ga.z));
        Vt[c*8+3][j] = tob(bf2f((short)rw.us[3]) * (r * ga.w));
        Vt[c*8+4][j] = tob(bf2f((short)rw.us[4]) * (r * gb.x));
        Vt[c*8+5][j] = tob(bf2f((short)rw.us[5]) * (r * gb.y));
        Vt[c*8+6][j] = tob(bf2f((short)rw.us[6]) * (r * gb.z));
        Vt[c*8+7][j] = tob(bf2f((short)rw.us[7]) * (r * gb.w));
      }
    }
  }
  __syncthreads();                          // the only block-wide barrier

  // ---- Q fragments direct from global (A-frag: row = lane&15, k = (lane>>4)*8 + kb) ----
  const int ml = lane & 15, k0 = (lane >> 4)*8;
  const int mrow = w*16 + ml;
  const int pA = (wx*8 + (mrow>>3))*192 + wy*8 + (mrow&7);
  const float rvA = rmsf(rs_v[pA]), rcA = rmsf(rs_c[pA]);
  bf16x8 qf0, qf1, qf2;
  {
    uint4 r0 = *(const uint4*)(Y0 + (size_t)pA*1152 + h*48 + k0);            // k in [0,32): values, rms
    float4 ga = *(const float4*)&sq[k0],      gb = *(const float4*)&sq[k0+4];
    qf0 = pack8g(r0, rvA, ga, gb);
    const bf16* s1 = (k0 < 16) ? (Y0 + (size_t)pA*1152 + h*48 + 32 + k0)     // k in [32,48): values raw
                               : (Yc + (size_t)pA*768  + h*48 + (k0 - 16));  // k in [48,64): coords
    float r1 = (k0 < 16) ? 1.0f : rcA;
    uint4 raw1 = *(const uint4*)s1;
    ga = *(const float4*)&sq[32+k0]; gb = *(const float4*)&sq[36+k0];
    qf1 = pack8g(raw1, r1, ga, gb);
    uint4 r2 = *(const uint4*)(Yc + (size_t)pA*768 + h*48 + 16 + k0);        // k in [64,96): coords
    ga = *(const float4*)&sq[64+k0]; gb = *(const float4*)&sq[68+k0];
    qf2 = pack8g(r2, rcA, ga, gb);
  }

  // ---- QK^T: wave w covers S rows [w*16, w*16+16), all 64 cols, K=96 ----
  f32x4 acc[4] = {};
  #pragma unroll
  for (int nt = 0; nt < 4; nt++) {
    bf16x8 b0 = *(const bf16x8*)&Ks[nt*16 + ml][k0];
    bf16x8 b1 = *(const bf16x8*)&Ks[nt*16 + ml][32 + k0];
    bf16x8 b2 = *(const bf16x8*)&Ks[nt*16 + ml][64 + k0];
    acc[nt] = __builtin_amdgcn_mfma_f32_16x16x32_bf16(qf0, b0, acc[nt], 0, 0, 0);
    acc[nt] = __builtin_amdgcn_mfma_f32_16x16x32_bf16(qf1, b1, acc[nt], 0, 0, 0);
    acc[nt] = __builtin_amdgcn_mfma_f32_16x16x32_bf16(qf2, b2, acc[nt], 0, 0, 0);
  }

  // ---- bias + mask + in-register softmax (row = 16-lane group, 4 regs x 4 col-tiles) ----
  const bool rowm = ((row0 >> 3) + wx) == 23;
  const bool colm = (wy == 23);
  const int g4 = (lane >> 4)*4;
  float pv[4][4];
  float inv_[4];
  #pragma unroll
  for (int i = 0; i < 4; i++) {
    int r = w*16 + g4 + i;
    int txi = r >> 3, tyi = r & 7;
    #pragma unroll
    for (int nt = 0; nt < 4; nt++) {
      int j = nt*16 + ml;
      int txj = j >> 3, tyj = j & 7;
      float v = acc[nt][i] + poss[(txj - txi + 7)*15 + (tyj - tyi + 7)];
      if ((rowm && ((txi >= 4) != (txj >= 4))) || (colm && ((tyi >= 4) != (tyj >= 4)))) v = -1e30f;
      pv[i][nt] = v;
    }
    float mx = fmaxf(fmaxf(pv[i][0], pv[i][1]), fmaxf(pv[i][2], pv[i][3]));
    #pragma unroll
    for (int m = 1; m < 16; m <<= 1) mx = fmaxf(mx, __shfl_xor(mx, m));
    float s0 = 0.f;
    #pragma unroll
    for (int nt = 0; nt < 4; nt++) { pv[i][nt] = __expf(pv[i][nt] - mx); s0 += pv[i][nt]; }
    #pragma unroll
    for (int m = 1; m < 16; m <<= 1) s0 += __shfl_xor(s0, m);
    inv_[i] = 1.f / s0;
  }
  #pragma unroll
  for (int i = 0; i < 4; i++)
  #pragma unroll
  for (int nt = 0; nt < 4; nt++)
    Pb[w*16 + g4 + i][nt*16 + ml] = tob(pv[i][nt]);   // un-normalized; 1/sum folded into O

  // ---- PV: O[16x48] per wave, K=64.  A = Pb (own rows), B = Vt (transposed V) ----
  f32x4 o0 = {}, o1 = {}, o2 = {};
  {
    bf16x8 a0 = *(const bf16x8*)&Pb[w*16 + ml][k0];
    bf16x8 b;
    b = *(const bf16x8*)&Vt[ 0 + ml][k0];      o0 = __builtin_amdgcn_mfma_f32_16x16x32_bf16(a0, b, o0, 0, 0, 0);
    b = *(const bf16x8*)&Vt[16 + ml][k0];      o1 = __builtin_amdgcn_mfma_f32_16x16x32_bf16(a0, b, o1, 0, 0, 0);
    b = *(const bf16x8*)&Vt[32 + ml][k0];      o2 = __builtin_amdgcn_mfma_f32_16x16x32_bf16(a0, b, o2, 0, 0, 0);
    bf16x8 a1 = *(const bf16x8*)&Pb[w*16 + ml][32 + k0];
    b = *(const bf16x8*)&Vt[ 0 + ml][32 + k0]; o0 = __builtin_amdgcn_mfma_f32_16x16x32_bf16(a1, b, o0, 0, 0, 0);
    b = *(const bf16x8*)&Vt[16 + ml][32 + k0]; o1 = __builtin_amdgcn_mfma_f32_16x16x32_bf16(a1, b, o1, 0, 0, 0);
    b = *(const bf16x8*)&Vt[32 + ml][32 + k0]; o2 = __builtin_amdgcn_mfma_f32_16x16x32_bf16(a1, b, o2, 0, 0, 0);
  }

  // ---- O repack into Pb (own rows, wave-private) then vectorized global store ----
  #pragma unroll
  for (int i = 0; i < 4; i++) {
    Pb[w*16 + g4 + i][     ml] = tob(o0[i] * inv_[i]);
    Pb[w*16 + g4 + i][16 + ml] = tob(o1[i] * inv_[i]);
    Pb[w*16 + g4 + i][32 + ml] = tob(o2[i] * inv_[i]);
  }
  #pragma unroll
  for (int s2 = 0; s2 < 3; s2++) {
    int u = s2*64 + lane;                 // 192 units: 16 rows x 12 uint2-segments
    int row = u / 12, seg = u - row*12;
    int rr = w*16 + row;
    int pC = (wx*8 + (rr>>3))*192 + wy*8 + (rr&7);
    uint2 d = *(const uint2*)&Pb[rr][seg*4];
    *(uint2*)(y_att + (size_t)pC*384 + h*48 + seg*4) = d;
  }
}

extern "C" void kernel_launch(void* const* d_in, const int* in_sizes, int n_in,
                              void* d_out, int out_size, void* d_ws, size_t ws_size,
                              hipStream_t stream)
{
  const float* values = (const float*)d_in[0];
  const float* coords = (const float*)d_in[1];
  const float* W_vqk  = (const float*)d_in[2];
  const float* b_vqk  = (const float*)d_in[3];
  const float* g_vqk  = (const float*)d_in[4];
  const float* W_vv   = (const float*)d_in[5];
  const float* b_vv   = (const float*)d_in[6];
  const float* W_cqk  = (const float*)d_in[7];
  const float* b_cqk  = (const float*)d_in[8];
  const float* g_cqk  = (const float*)d_in[9];
  const float* lam    = (const float*)d_in[10];
  const float* pos    = (const float*)d_in[11];
  const float* W_ov   = (const float*)d_in[12];
  const float* b_ov   = (const float*)d_in[13];
  float* out = (float*)d_out;
  (void)in_sizes; (void)n_in; (void)out_size;

  // Region size: one full batch (192 rows) if workspace allows, else 64-row chunks (verified fallback).
  // Layout (bytes): weights/biases fixed 1391616, then Y0/Yc/rs_v/rs_c/y_att sized by npix.
  const size_t FIX = 1391616;
  size_t need_full = FIX + (size_t)36864*1152*2 + (size_t)36864*768*2 + 2*(size_t)36864*4 + (size_t)36864*384*2;
  const bool full = (ws_size >= need_full);
  const int nrows = full ? 192 : 64;
  const int npix  = nrows*192;

  char* ws = (char*)d_ws;
  bf16*  W1Tp  = (bf16*)(ws + 0);
  bf16*  WcTp  = (bf16*)(ws + 884736);
  bf16*  WoT   = (bf16*)(ws + 1081344);
  float* bP0   = (float*)(ws + 1376256);
  float* bPc   = (float*)(ws + 1380864);
  float* gvP   = (float*)(ws + 1383936);
  float* gcP   = (float*)(ws + 1388544);
  size_t off = FIX;
  bf16*  Y0    = (bf16*)(ws + off);  off += (size_t)npix*1152*2;
  bf16*  Yc    = (bf16*)(ws + off);  off += (size_t)npix*768*2;
  float* rs_v  = (float*)(ws + off); off += (size_t)npix*4;
  float* rs_c  = (float*)(ws + off); off += (size_t)npix*4;
  bf16*  y_att = (bf16*)(ws + off);

  int wgrid = (691968 + 2*npix + 255)/256;
  wprep_k<<<wgrid, 256, 0, stream>>>(W_vqk, W_vv, W_cqk, W_ov, b_vqk, b_vv, b_cqk, g_vqk, g_cqk,
                                     W1Tp, WcTp, WoT, bP0, bPc, gvP, gcP, rs_v, rs_c, npix);

  const int nreg = full ? 2 : 6;          // regions: per-batch (full) or per-(batch,third) chunks
  for (int rg = 0; rg < nreg; rg++) {
    int bb   = full ? rg : rg/3;
    int row0 = full ? 0  : (rg - bb*3)*64;
    int pix0 = bb*36864 + row0*192;
    dim3 gq(npix/128, 9), gc(npix/128, 6), ga((nrows/8)*24, 8), go(npix/64, 3);
    gemm_k<0><<<gq, 256, 0, stream>>>(values, nullptr, W1Tp, bP0, Y0, nullptr, rs_v,
                                      nullptr, nullptr, bb, row0, 0);
    gemm_k<1><<<gc, 256, 0, stream>>>(coords, nullptr, WcTp, bPc, Yc, nullptr, rs_c,
                                      nullptr, nullptr, bb, row0, 0);
    attn_k<<<ga, 256, 0, stream>>>(Y0, Yc, rs_v, rs_c, gvP, gcP, lam, pos, y_att, row0);
    gemm_k<2><<<go, 256, 0, stream>>>(nullptr, y_att, WoT, b_ov, nullptr, out, nullptr,
                                      rs_v, rs_c, 0, 0, pix0);
  }
}